// Round 12
// baseline (68.454 us; speedup 1.0000x reference)
//
#include <hip/hip_runtime.h>
#include <hip/hip_bf16.h>
#include <math.h>

#define EPSF 1e-8f
#define HPARAM 0.1f
#define FB 32      // faces per block (surfA role)
#define NC 16      // target chunks (surfA role)
#define VB 16      // verts per block (chamA role)
#define NCM 16     // target chunks (chamA role)
#define TI 4       // i-faces per pair block
#define TTS 16     // targets per thread (surfB)
#define TTC 16     // targets per thread (chamB)
#define NCS 4      // pred chunks (surfB)
#define NCC 4      // vert chunks (chamB)
#define GATE2 1.0f // cd2 cutoff: gate<=4.5e-5, skipped mass ~1e-4 << 1.66 threshold

__device__ __forceinline__ float waveReduceSum(float v) {
#pragma unroll
    for (int o = 32; o > 0; o >>= 1) v += __shfl_down(v, o, 64);
    return v;
}
__device__ __forceinline__ float waveReduceMin(float v) {
#pragma unroll
    for (int o = 32; o > 0; o >>= 1) v = fminf(v, __shfl_down(v, o, 64));
    return v;
}
__device__ __forceinline__ float blockSum(float s, float* red4) {
    s = waveReduceSum(s);
    int lane = threadIdx.x & 63, wid = threadIdx.x >> 6;
    if (lane == 0) red4[wid] = s;
    __syncthreads();
    return red4[0] + red4[1] + red4[2] + red4[3];
}
__device__ __forceinline__ float clamp01(float x) {
    return fminf(fmaxf(x, 0.0f), 1.0f);
}

// ---------------- fused precompute ----------------
__global__ __launch_bounds__(256) void k_pre(
    const float* __restrict__ pv, const int* __restrict__ pf,
    const float* __restrict__ tv, const int* __restrict__ tf,
    float* __restrict__ tri, float4* __restrict__ bp4,
    float* __restrict__ nhat, float* __restrict__ d0,
    float4* __restrict__ bt4, float4* __restrict__ tv4, float4* __restrict__ pv4,
    int N, int F, int M, int Ft)
{
    int nbF = (F + 255) >> 8, nbFt = (Ft + 255) >> 8, nbM = (M + 255) >> 8;
    int b = blockIdx.x, tid = threadIdx.x;
    if (b < nbF) {
        int i = b * 256 + tid;
        if (i >= F) return;
        int a = pf[i * 3 + 0], bb = pf[i * 3 + 1], c = pf[i * 3 + 2];
        float v0x = pv[a * 3], v0y = pv[a * 3 + 1], v0z = pv[a * 3 + 2];
        float v1x = pv[bb * 3], v1y = pv[bb * 3 + 1], v1z = pv[bb * 3 + 2];
        float v2x = pv[c * 3], v2y = pv[c * 3 + 1], v2z = pv[c * 3 + 2];
        tri[i * 9 + 0] = v0x; tri[i * 9 + 1] = v0y; tri[i * 9 + 2] = v0z;
        tri[i * 9 + 3] = v1x; tri[i * 9 + 4] = v1y; tri[i * 9 + 5] = v1z;
        tri[i * 9 + 6] = v2x; tri[i * 9 + 7] = v2y; tri[i * 9 + 8] = v2z;
        float bx = (v0x + v1x + v2x) / 3.0f;
        float by = (v0y + v1y + v2y) / 3.0f;
        float bz = (v0z + v1z + v2z) / 3.0f;
        bp4[i] = make_float4(bx, by, bz, bx * bx + by * by + bz * bz);
        float e1x = v1x - v0x, e1y = v1y - v0y, e1z = v1z - v0z;
        float e2x = v2x - v0x, e2y = v2y - v0y, e2z = v2z - v0z;
        float nx = e1y * e2z - e1z * e2y;
        float ny = e1z * e2x - e1x * e2z;
        float nz = e1x * e2y - e1y * e2x;
        float nrm = sqrtf(nx * nx + ny * ny + nz * nz);
        float inv = 1.0f / (nrm + EPSF);
        float hx = nx * inv, hy = ny * inv, hz = nz * inv;
        nhat[i * 3 + 0] = hx; nhat[i * 3 + 1] = hy; nhat[i * 3 + 2] = hz;
        d0[i] = hx * v0x + hy * v0y + hz * v0z;
    } else if (b < nbF + nbFt) {
        int j = (b - nbF) * 256 + tid;
        if (j >= Ft) return;
        int a = tf[j * 3 + 0], bb = tf[j * 3 + 1], c = tf[j * 3 + 2];
        float bx = (tv[a * 3 + 0] + tv[bb * 3 + 0] + tv[c * 3 + 0]) / 3.0f;
        float by = (tv[a * 3 + 1] + tv[bb * 3 + 1] + tv[c * 3 + 1]) / 3.0f;
        float bz = (tv[a * 3 + 2] + tv[bb * 3 + 2] + tv[c * 3 + 2]) / 3.0f;
        bt4[j] = make_float4(bx, by, bz, bx * bx + by * by + bz * bz);
    } else if (b < nbF + nbFt + nbM) {
        int j = (b - nbF - nbFt) * 256 + tid;
        if (j >= M) return;
        float x = tv[j * 3], y = tv[j * 3 + 1], z = tv[j * 3 + 2];
        tv4[j] = make_float4(x, y, z, x * x + y * y + z * z);
    } else {
        int j = (b - nbF - nbFt - nbM) * 256 + tid;
        if (j >= N) return;
        float x = pv[j * 3], y = pv[j * 3 + 1], z = pv[j * 3 + 2];
        pv4[j] = make_float4(x, y, z, x * x + y * y + z * z);
    }
}

// ---------------- mega kernel: pair / surfA / surfB / chamA / chamB ----------------
// (256,2): cap occupancy at 2 waves/EU so the allocator keeps the FB=32 / TT=16
// invariant arrays register-resident (VGPR<=256) instead of reloading in hot loops.
__global__ __launch_bounds__(256, 2) void k_mega(
    const float4* __restrict__ pv4, const float4* __restrict__ tv4,
    const float* __restrict__ tri, const float4* __restrict__ bp4,
    const float* __restrict__ nhat, const float* __restrict__ d0,
    const float* __restrict__ probs, const float4* __restrict__ bt4,
    float* __restrict__ chamAp, float* __restrict__ chamBp,
    float* __restrict__ surfAp, float* __restrict__ surfBp,
    float* __restrict__ pairp,
    int N, int F, int M, int Ft,
    int o1, int o2, int o3, int o4)
{
    __shared__ float4 sh4[576];      // 9216 B union: surfB/chamB tiles / pair f-tri tile
    __shared__ float red4[4];
    int b = blockIdx.x;
    int tid = threadIdx.x;

    if (b < o1) {
        // ---- pair terms FIRST (heaviest; short blocks fill the tail) ----
        __shared__ int slist[256];
        __shared__ int scnt[4];
        int rb = b;
        int bpF = F >> 8;                    // 4
        int ig = rb / bpF;
        int fg = rb % bpF;
        float* sTri = (float*)sh4;
        for (int t = tid; t < 256 * 9; t += 256) sTri[t] = tri[fg * 256 * 9 + t];
        __syncthreads();

        int lane = tid & 63, wid = tid >> 6;
        float contrib = 0.0f;
#pragma unroll 1
        for (int ii = 0; ii < TI; ++ii) {
            int i = ig * TI + ii;
            float ti[9];
#pragma unroll
            for (int v = 0; v < 9; ++v) ti[v] = tri[i * 9 + v];
            float nix = nhat[i * 3], niy = nhat[i * 3 + 1], niz = nhat[i * 3 + 2];
            float di = d0[i];
            float4 bi = bp4[i];
            float pi = probs[i];
            // i-edge invariants (block-uniform)
            float p1xa[3], p1ya[3], p1za[3], d1xa[3], d1ya[3], d1za[3], ava[3], rava[3];
#pragma unroll
            for (int e1 = 0; e1 < 3; ++e1) {
                int e1n = (e1 == 2) ? 0 : e1 + 1;
                p1xa[e1] = ti[e1 * 3]; p1ya[e1] = ti[e1 * 3 + 1]; p1za[e1] = ti[e1 * 3 + 2];
                d1xa[e1] = ti[e1n * 3] - p1xa[e1];
                d1ya[e1] = ti[e1n * 3 + 1] - p1ya[e1];
                d1za[e1] = ti[e1n * 3 + 2] - p1za[e1];
                ava[e1] = d1xa[e1] * d1xa[e1] + d1ya[e1] * d1ya[e1] + d1za[e1] * d1za[e1];
                rava[e1] = __builtin_amdgcn_rcpf(ava[e1] + EPSF);
            }
            // gate + compaction (indices only; cd2 recomputed in body)
            int f = fg * 256 + tid;
            float4 bft = bp4[f];
            float cdx = bi.x - bft.x, cdy = bi.y - bft.y, cdz = bi.z - bft.z;
            float cd2 = cdx * cdx + cdy * cdy + cdz * cdz;
            bool pass = (f != i) && (cd2 <= GATE2);
            unsigned long long mask = __ballot(pass);
            if (lane == 0) scnt[wid] = __popcll(mask);
            __syncthreads();
            int base = 0;
#pragma unroll
            for (int w = 0; w < 4; ++w) base += (w < wid) ? scnt[w] : 0;
            int nCand = scnt[0] + scnt[1] + scnt[2] + scnt[3];
            int pfx = __popcll(mask & ((1ULL << lane) - 1ULL));
            if (pass) slist[base + pfx] = tid;
            __syncthreads();

            if (tid < nCand) {
                int src = slist[tid];
                float4 bf = bp4[fg * 256 + src];
                float rcx = bi.x - bf.x, rcy = bi.y - bf.y, rcz = bi.z - bf.z;
                float gate = __expf(-10.0f * (rcx * rcx + rcy * rcy + rcz * rcz));
                float tf9[9];
#pragma unroll
                for (int v = 0; v < 9; ++v) tf9[v] = sTri[src * 9 + v];
                float s0 = nix * tf9[0] + niy * tf9[1] + niz * tf9[2] - di;
                float s1 = nix * tf9[3] + niy * tf9[4] + niz * tf9[5] - di;
                float s2 = nix * tf9[6] + niy * tf9[7] + niz * tf9[8] - di;
                float smax = fmaxf(fmaxf(s0, s1), s2);
                float smin = fminf(fminf(s0, s1), s2);
                float pen_col = fmaxf(-(smax * smin), 0.0f);
                float dp = fabsf(nix * bf.x + niy * bf.y + niz * bf.z - di);
                float pen_ov = fmaxf(HPARAM - dp, 0.0f);
                // f-edge invariants
                float q2x[3], q2y[3], q2z[3], e2xa[3], e2ya[3], e2za[3], eva[3], reva[3];
#pragma unroll
                for (int e2 = 0; e2 < 3; ++e2) {
                    int e2n = (e2 == 2) ? 0 : e2 + 1;
                    q2x[e2] = tf9[e2 * 3]; q2y[e2] = tf9[e2 * 3 + 1]; q2z[e2] = tf9[e2 * 3 + 2];
                    e2xa[e2] = tf9[e2n * 3] - q2x[e2];
                    e2ya[e2] = tf9[e2n * 3 + 1] - q2y[e2];
                    e2za[e2] = tf9[e2n * 3 + 2] - q2z[e2];
                    eva[e2] = e2xa[e2] * e2xa[e2] + e2ya[e2] * e2ya[e2] + e2za[e2] * e2za[e2];
                    reva[e2] = __builtin_amdgcn_rcpf(eva[e2] + EPSF);
                }
                float d2v[9];
                float dminv = 3.4e38f;
#pragma unroll
                for (int e1 = 0; e1 < 3; ++e1) {
#pragma unroll
                    for (int e2 = 0; e2 < 3; ++e2) {
                        float rx = p1xa[e1] - q2x[e2], ry = p1ya[e1] - q2y[e2], rz = p1za[e1] - q2z[e2];
                        float f_ = e2xa[e2] * rx + e2ya[e2] * ry + e2za[e2] * rz;
                        float c_ = d1xa[e1] * rx + d1ya[e1] * ry + d1za[e1] * rz;
                        float b_ = d1xa[e1] * e2xa[e2] + d1ya[e1] * e2ya[e2] + d1za[e1] * e2za[e2];
                        float denom = ava[e1] * eva[e2] - b_ * b_;
                        float rden = __builtin_amdgcn_rcpf(denom + EPSF);
                        float ss = clamp01(fmaf(-c_, eva[e2], b_ * f_) * rden);
                        float tt = clamp01(fmaf(b_, ss, f_) * reva[e2]);
                        ss = clamp01(fmaf(b_, tt, -c_) * rava[e1]);
                        float vx = fmaf(ss, d1xa[e1], p1xa[e1]) - fmaf(tt, e2xa[e2], q2x[e2]);
                        float vy = fmaf(ss, d1ya[e1], p1ya[e1]) - fmaf(tt, e2ya[e2], q2y[e2]);
                        float vz = fmaf(ss, d1za[e1], p1za[e1]) - fmaf(tt, e2za[e2], q2z[e2]);
                        float dd = vx * vx + vy * vy + vz * vz;
                        d2v[e1 * 3 + e2] = dd;
                        dminv = fminf(dminv, dd);
                    }
                }
                float pen_edge = 0.0f;
                // relu(H - sqrt(d2+eps)) > 0  <=>  d2 + eps < H^2  (exact)
                if (dminv + EPSF < HPARAM * HPARAM) {
#pragma unroll
                    for (int qq = 0; qq < 9; ++qq)
                        pen_edge += fmaxf(HPARAM - __builtin_amdgcn_sqrtf(d2v[qq] + EPSF), 0.0f);
                }
                contrib += pi * gate * (pen_col + pen_ov + pen_edge);
            }
            __syncthreads();   // protect slist/scnt before next i
        }
        float s = blockSum(contrib, red4);
        if (tid == 0) pairp[rb] = s;
    } else if (b < o2) {
        // ---- surfA: FB=32 faces (regs) x NC target chunks; 4-op inner, psq deferred ----
        int rb = b - o1;
        int nFG = F / FB;                 // 32
        int fg = rb % nFG, chunk = rb / nFG;
        int i0 = fg * FB;
        float m2x[FB], m2y[FB], m2z[FB], m[FB];
#pragma unroll
        for (int k = 0; k < FB; ++k) {
            float4 bb = bp4[i0 + k];
            m2x[k] = -2.0f * bb.x; m2y[k] = -2.0f * bb.y; m2z[k] = -2.0f * bb.z;
            m[k] = 3.4e38f;
        }
        int TC = Ft / NC;
        int jend = chunk * TC + TC;
        for (int j = chunk * TC + tid; j < jend; j += 256) {
            float4 t = bt4[j];
#pragma unroll
            for (int k = 0; k < FB; ++k) {
                float acc = fmaf(m2x[k], t.x, fmaf(m2y[k], t.y, fmaf(m2z[k], t.z, t.w)));
                m[k] = fminf(m[k], acc);
            }
        }
        __shared__ float redA[4][FB];
#pragma unroll
        for (int k = 0; k < FB; ++k) m[k] = waveReduceMin(m[k]);
        int lane = tid & 63, wid = tid >> 6;
        if (lane == 0) {
#pragma unroll
            for (int k = 0; k < FB; ++k) redA[wid][k] = m[k];
        }
        __syncthreads();
        if (tid < FB) {
            float r = fminf(fminf(redA[0][tid], redA[1][tid]),
                            fminf(redA[2][tid], redA[3][tid]));
            surfAp[(i0 + tid) * NC + chunk] = r + bp4[i0 + tid].w;   // defer psq
        }
    } else if (b < o3) {
        // ---- surfB: TTS=16 targets/thread, transformed pred chunk in LDS ----
        int rb = b - o2;
        int nJG = Ft / (256 * TTS);       // 16
        int jg = rb % nJG, c = rb / nJG;
        int CH = F / NCS;                 // 256
        for (int t = tid; t < CH; t += 256) {
            float4 p = bp4[c * CH + t];
            sh4[t] = make_float4(-2.0f * p.x, -2.0f * p.y, -2.0f * p.z, p.w);
        }
        __syncthreads();
        int q = Ft / TTS;                 // 4096
        int j0 = jg * 256 + tid;
        float4 tv8[TTS];
        float mm[TTS];
#pragma unroll
        for (int k = 0; k < TTS; ++k) { tv8[k] = bt4[j0 + k * q]; mm[k] = 3.4e38f; }
#pragma unroll 2
        for (int i = 0; i < CH; ++i) {
            float4 p = sh4[i];
#pragma unroll
            for (int k = 0; k < TTS; ++k)
                mm[k] = fminf(mm[k], fmaf(p.x, tv8[k].x, fmaf(p.y, tv8[k].y, fmaf(p.z, tv8[k].z, p.w))));
        }
#pragma unroll
        for (int k = 0; k < TTS; ++k)
            surfBp[c * Ft + j0 + k * q] = mm[k] + tv8[k].w;   // defer |t|^2
    } else if (b < o4) {
        // ---- chamA: VB=16 verts (regs) x NCM target chunks ----
        int rb = b - o3;
        int nVG = N / VB;                 // 32
        int vg = rb % nVG, chunk = rb / nVG;
        int v0 = vg * VB;
        float m2x[VB], m2y[VB], m2z[VB], m[VB];
#pragma unroll
        for (int k = 0; k < VB; ++k) {
            float4 p = pv4[v0 + k];
            m2x[k] = -2.0f * p.x; m2y[k] = -2.0f * p.y; m2z[k] = -2.0f * p.z;
            m[k] = 3.4e38f;
        }
        int TC = M / NCM;
        int jend = chunk * TC + TC;
        for (int j = chunk * TC + tid; j < jend; j += 256) {
            float4 t = tv4[j];
#pragma unroll
            for (int k = 0; k < VB; ++k) {
                float acc = fmaf(m2x[k], t.x, fmaf(m2y[k], t.y, fmaf(m2z[k], t.z, t.w)));
                m[k] = fminf(m[k], acc);
            }
        }
        __shared__ float redC[4][VB];
#pragma unroll
        for (int k = 0; k < VB; ++k) m[k] = waveReduceMin(m[k]);
        int lane = tid & 63, wid = tid >> 6;
        if (lane == 0) {
#pragma unroll
            for (int k = 0; k < VB; ++k) redC[wid][k] = m[k];
        }
        __syncthreads();
        if (tid < VB) {
            float r = fminf(fminf(redC[0][tid], redC[1][tid]),
                            fminf(redC[2][tid], redC[3][tid]));
            chamAp[(v0 + tid) * NCM + chunk] = r + pv4[v0 + tid].w;
        }
    } else {
        // ---- chamB: TTC=16 targets/thread, transformed vert chunk in LDS ----
        int rb = b - o4;
        int nJG = M / (256 * TTC);        // 8
        int jg = rb % nJG, c = rb / nJG;
        int CH = N / NCC;                 // 128
        for (int t = tid; t < CH; t += 256) {
            float4 p = pv4[c * CH + t];
            sh4[t] = make_float4(-2.0f * p.x, -2.0f * p.y, -2.0f * p.z, p.w);
        }
        __syncthreads();
        int q = M / TTC;                  // 2048
        int j0 = jg * 256 + tid;
        float4 tv8[TTC];
        float mm[TTC];
#pragma unroll
        for (int k = 0; k < TTC; ++k) { tv8[k] = tv4[j0 + k * q]; mm[k] = 3.4e38f; }
#pragma unroll 2
        for (int i = 0; i < CH; ++i) {
            float4 p = sh4[i];
#pragma unroll
            for (int k = 0; k < TTC; ++k)
                mm[k] = fminf(mm[k], fmaf(p.x, tv8[k].x, fmaf(p.y, tv8[k].y, fmaf(p.z, tv8[k].z, p.w))));
        }
#pragma unroll
        for (int k = 0; k < TTC; ++k)
            chamBp[c * M + j0 + k * q] = mm[k] + tv8[k].w;
    }
}

// ---------------- generic reduce: every block emits one weighted partial ----------------
__global__ __launch_bounds__(256) void k_reduce(
    const float* __restrict__ surfBp, int Ft, float invFt,
    const float* __restrict__ chamBp, int M, float invM,
    const float* __restrict__ chamAp, int N, float invN,
    const float* __restrict__ surfAp, const float* __restrict__ probs, int F, float invF,
    const float* __restrict__ pairp, int nPB, float pairScale,
    float* __restrict__ smallp)
{
    __shared__ float red4[4];
    int b = blockIdx.x, tid = threadIdx.x;
    int nbS = Ft >> 8, nbC = M >> 8, nbA = N >> 8, nbSA = F >> 8;
    float s;
    if (b < nbS) {
        int j = b * 256 + tid;
        float r = 3.4e38f;
#pragma unroll
        for (int c = 0; c < NCS; ++c) r = fminf(r, surfBp[c * Ft + j]);
        s = r * invFt;
    } else if (b < nbS + nbC) {
        int j = (b - nbS) * 256 + tid;
        float r = 3.4e38f;
#pragma unroll
        for (int c = 0; c < NCC; ++c) r = fminf(r, chamBp[c * M + j]);
        s = r * invM;
    } else if (b < nbS + nbC + nbA) {
        int v = (b - nbS - nbC) * 256 + tid;
        float r = 3.4e38f;
#pragma unroll
        for (int c = 0; c < NCM; ++c) r = fminf(r, chamAp[v * NCM + c]);
        s = r * invN;
    } else if (b < nbS + nbC + nbA + nbSA) {
        int i = (b - nbS - nbC - nbA) * 256 + tid;
        float r = 3.4e38f;
#pragma unroll
        for (int c = 0; c < NC; ++c) r = fminf(r, surfAp[i * NC + c]);
        s = probs[i] * r * invF;
    } else {
        int t = (b - nbS - nbC - nbA - nbSA) * 256 + tid;
        s = (t < nPB) ? pairp[t] * pairScale : 0.0f;
    }
    float r = blockSum(s, red4);
    if (tid == 0) smallp[b] = r;
}

// ---------------- tiny final sum ----------------
__global__ __launch_bounds__(256) void k_fin(
    const float* __restrict__ smallp, int n, float* __restrict__ out)
{
    __shared__ float red4[4];
    float s = 0.0f;
    for (int t = threadIdx.x; t < n; t += 256) s += smallp[t];
    float r = blockSum(s, red4);
    if (threadIdx.x == 0) out[0] = r;
}

extern "C" void kernel_launch(void* const* d_in, const int* in_sizes, int n_in,
                              void* d_out, int out_size, void* d_ws, size_t ws_size,
                              hipStream_t stream) {
    const float* pv    = (const float*)d_in[0];
    const float* probs = (const float*)d_in[1];
    const float* tv    = (const float*)d_in[2];
    const int*   pf    = (const int*)d_in[3];
    const int*   tf    = (const int*)d_in[4];
    float* out = (float*)d_out;

    int N  = in_sizes[0] / 3;   // 512
    int F  = in_sizes[1];       // 1024
    int M  = in_sizes[2] / 3;   // 32768
    int Ft = in_sizes[4] / 3;   // 65536

    int bpF = F >> 8;                 // 4
    int nPB = (F / TI) * bpF;         // 1024 pair blocks

    float* ws = (float*)d_ws;
    float* w_tri    = ws;                       // F*9
    float* w_nhat   = w_tri + F * 9;            // F*3
    float* w_d0     = w_nhat + F * 3;           // F
    float4* w_bp4   = (float4*)(w_d0 + F);      // F (16B aligned)
    float4* w_bt4   = w_bp4 + F;                // Ft
    float4* w_tv4   = w_bt4 + Ft;               // M
    float4* w_pv4   = w_tv4 + M;                // N
    float* w_chamAp = (float*)(w_pv4 + N);      // N*NCM
    float* w_surfAp = w_chamAp + N * NCM;       // F*NC
    float* w_pair   = w_surfAp + F * NC;        // nPB
    float* w_small  = w_pair + nPB;             // <=512
    float* w_surfBp = w_small + 512;            // NCS*Ft (1 MB)
    float* w_chamBp = w_surfBp + (size_t)NCS * Ft; // NCC*M (0.5 MB)

    // mega-grid role offsets: pair FIRST, then surfA, surfB, chamA, chamB
    int o1 = nPB;                             // 1024 pair
    int o2 = o1 + (F / FB) * NC;              // +512 surfA
    int o3 = o2 + (Ft / (256 * TTS)) * NCS;   // +64 surfB
    int o4 = o3 + (N / VB) * NCM;             // +512 chamA
    int gTot = o4 + (M / (256 * TTC)) * NCC;  // +32 chamB

    int nSmall = (Ft >> 8) + (M >> 8) + (N >> 8) + (F >> 8) + ((nPB + 255) >> 8); // 394
    int gPre = (F + 255) / 256 + (Ft + 255) / 256 + (M + 255) / 256 + (N + 255) / 256;

    k_pre<<<gPre, 256, 0, stream>>>(
        pv, pf, tv, tf, w_tri, w_bp4, w_nhat, w_d0, w_bt4, w_tv4, w_pv4,
        N, F, M, Ft);
    k_mega<<<gTot, 256, 0, stream>>>(
        w_pv4, w_tv4, w_tri, w_bp4, w_nhat, w_d0, probs, w_bt4,
        w_chamAp, w_chamBp, w_surfAp, w_surfBp, w_pair,
        N, F, M, Ft, o1, o2, o3, o4);
    k_reduce<<<nSmall, 256, 0, stream>>>(
        w_surfBp, Ft, 1.0f / (float)Ft,
        w_chamBp, M, 1.0f / (float)M,
        w_chamAp, N, 1.0f / (float)N,
        w_surfAp, probs, F, 1.0f / (float)F,
        w_pair, nPB, 10.0f / (float)F,
        w_small);
    k_fin<<<1, 256, 0, stream>>>(w_small, nSmall, out);
}

// Round 13
// 44.711 us; speedup vs baseline: 1.5311x; 1.5311x over previous
//
#include <hip/hip_runtime.h>
#include <hip/hip_bf16.h>
#include <math.h>

#define EPSF 1e-8f
#define HPARAM 0.1f
#define FB 16      // faces per block (surfA role)
#define NC 16      // target chunks (surfA role)
#define VB 8       // verts per block (chamA role)
#define NCM 16     // target chunks (chamA role)
#define TI 4       // i-faces per pair block
#define TT 8       // targets per thread (surfB/chamB roles)
#define GATE2 1.0f // cd2 cutoff: gate<=4.5e-5, skipped mass ~1e-3 << 1.66 threshold

__device__ __forceinline__ float waveReduceSum(float v) {
#pragma unroll
    for (int o = 32; o > 0; o >>= 1) v += __shfl_down(v, o, 64);
    return v;
}
__device__ __forceinline__ float waveReduceMin(float v) {
#pragma unroll
    for (int o = 32; o > 0; o >>= 1) v = fminf(v, __shfl_down(v, o, 64));
    return v;
}
__device__ __forceinline__ float blockSum(float s, float* red4) {
    s = waveReduceSum(s);
    int lane = threadIdx.x & 63, wid = threadIdx.x >> 6;
    if (lane == 0) red4[wid] = s;
    __syncthreads();
    return red4[0] + red4[1] + red4[2] + red4[3];
}
__device__ __forceinline__ float clamp01(float x) {
    return fminf(fmaxf(x, 0.0f), 1.0f);
}

// ---------------- fused precompute ----------------
__global__ __launch_bounds__(256) void k_pre(
    const float* __restrict__ pv, const int* __restrict__ pf,
    const float* __restrict__ tv, const int* __restrict__ tf,
    float* __restrict__ tri, float4* __restrict__ bp4,
    float* __restrict__ nhat, float* __restrict__ d0,
    float4* __restrict__ bt4, float4* __restrict__ tv4, float4* __restrict__ pv4,
    int N, int F, int M, int Ft)
{
    int nbF = (F + 255) >> 8, nbFt = (Ft + 255) >> 8, nbM = (M + 255) >> 8;
    int b = blockIdx.x, tid = threadIdx.x;
    if (b < nbF) {
        int i = b * 256 + tid;
        if (i >= F) return;
        int a = pf[i * 3 + 0], bb = pf[i * 3 + 1], c = pf[i * 3 + 2];
        float v0x = pv[a * 3], v0y = pv[a * 3 + 1], v0z = pv[a * 3 + 2];
        float v1x = pv[bb * 3], v1y = pv[bb * 3 + 1], v1z = pv[bb * 3 + 2];
        float v2x = pv[c * 3], v2y = pv[c * 3 + 1], v2z = pv[c * 3 + 2];
        tri[i * 9 + 0] = v0x; tri[i * 9 + 1] = v0y; tri[i * 9 + 2] = v0z;
        tri[i * 9 + 3] = v1x; tri[i * 9 + 4] = v1y; tri[i * 9 + 5] = v1z;
        tri[i * 9 + 6] = v2x; tri[i * 9 + 7] = v2y; tri[i * 9 + 8] = v2z;
        float bx = (v0x + v1x + v2x) / 3.0f;
        float by = (v0y + v1y + v2y) / 3.0f;
        float bz = (v0z + v1z + v2z) / 3.0f;
        bp4[i] = make_float4(bx, by, bz, bx * bx + by * by + bz * bz);
        float e1x = v1x - v0x, e1y = v1y - v0y, e1z = v1z - v0z;
        float e2x = v2x - v0x, e2y = v2y - v0y, e2z = v2z - v0z;
        float nx = e1y * e2z - e1z * e2y;
        float ny = e1z * e2x - e1x * e2z;
        float nz = e1x * e2y - e1y * e2x;
        float nrm = sqrtf(nx * nx + ny * ny + nz * nz);
        float inv = 1.0f / (nrm + EPSF);
        float hx = nx * inv, hy = ny * inv, hz = nz * inv;
        nhat[i * 3 + 0] = hx; nhat[i * 3 + 1] = hy; nhat[i * 3 + 2] = hz;
        d0[i] = hx * v0x + hy * v0y + hz * v0z;
    } else if (b < nbF + nbFt) {
        int j = (b - nbF) * 256 + tid;
        if (j >= Ft) return;
        int a = tf[j * 3 + 0], bb = tf[j * 3 + 1], c = tf[j * 3 + 2];
        float bx = (tv[a * 3 + 0] + tv[bb * 3 + 0] + tv[c * 3 + 0]) / 3.0f;
        float by = (tv[a * 3 + 1] + tv[bb * 3 + 1] + tv[c * 3 + 1]) / 3.0f;
        float bz = (tv[a * 3 + 2] + tv[bb * 3 + 2] + tv[c * 3 + 2]) / 3.0f;
        bt4[j] = make_float4(bx, by, bz, bx * bx + by * by + bz * bz);
    } else if (b < nbF + nbFt + nbM) {
        int j = (b - nbF - nbFt) * 256 + tid;
        if (j >= M) return;
        float x = tv[j * 3], y = tv[j * 3 + 1], z = tv[j * 3 + 2];
        tv4[j] = make_float4(x, y, z, x * x + y * y + z * z);
    } else {
        int j = (b - nbF - nbFt - nbM) * 256 + tid;
        if (j >= N) return;
        float x = pv[j * 3], y = pv[j * 3 + 1], z = pv[j * 3 + 2];
        pv4[j] = make_float4(x, y, z, x * x + y * y + z * z);
    }
}

// ---------------- mega kernel: pair / surfA / surfB / chamA / chamB ----------------
// launch_bounds (256,2): cap occupancy target at 2 waves/EU so the register
// allocator can keep the FB=16 / TT=8 invariant arrays resident (VGPR<=256)
// instead of re-loading them inside the hot loops.
__global__ __launch_bounds__(256, 2) void k_mega(
    const float4* __restrict__ pv4, const float4* __restrict__ tv4,
    const float* __restrict__ tri, const float4* __restrict__ bp4,
    const float* __restrict__ nhat, const float* __restrict__ d0,
    const float* __restrict__ probs, const float4* __restrict__ bt4,
    float* __restrict__ chamAp, float* __restrict__ chamBp,
    float* __restrict__ surfAp, float* __restrict__ surfBp,
    float* __restrict__ pairp,
    int N, int F, int M, int Ft, int ncS, int ncC,
    int o1, int o2, int o3, int o4)
{
    __shared__ float4 sh4[1024];     // union: surfB/chamB tiles / pair f-tri tile
    __shared__ float red4[4];
    int b = blockIdx.x;
    int tid = threadIdx.x;

    if (b < o1) {
        // ---- pair terms FIRST (heaviest blocks start early; short blocks fill tail) ----
        __shared__ int slist[256];
        __shared__ int scnt[4];
        int rb = b;
        int bpF = F >> 8;                    // 4
        int ig = rb / bpF;
        int fg = rb % bpF;
        float* sTri = (float*)sh4;
        for (int t = tid; t < 256 * 9; t += 256) sTri[t] = tri[fg * 256 * 9 + t];
        __syncthreads();

        int lane = tid & 63, wid = tid >> 6;
        float contrib = 0.0f;
#pragma unroll 1
        for (int ii = 0; ii < TI; ++ii) {
            int i = ig * TI + ii;
            float ti[9];
#pragma unroll
            for (int v = 0; v < 9; ++v) ti[v] = tri[i * 9 + v];
            float nix = nhat[i * 3], niy = nhat[i * 3 + 1], niz = nhat[i * 3 + 2];
            float di = d0[i];
            float4 bi = bp4[i];
            float pi = probs[i];
            // i-edge invariants (block-uniform)
            float p1xa[3], p1ya[3], p1za[3], d1xa[3], d1ya[3], d1za[3], ava[3], rava[3];
#pragma unroll
            for (int e1 = 0; e1 < 3; ++e1) {
                int e1n = (e1 == 2) ? 0 : e1 + 1;
                p1xa[e1] = ti[e1 * 3]; p1ya[e1] = ti[e1 * 3 + 1]; p1za[e1] = ti[e1 * 3 + 2];
                d1xa[e1] = ti[e1n * 3] - p1xa[e1];
                d1ya[e1] = ti[e1n * 3 + 1] - p1ya[e1];
                d1za[e1] = ti[e1n * 3 + 2] - p1za[e1];
                ava[e1] = d1xa[e1] * d1xa[e1] + d1ya[e1] * d1ya[e1] + d1za[e1] * d1za[e1];
                rava[e1] = __builtin_amdgcn_rcpf(ava[e1] + EPSF);
            }
            // gate + compaction (indices only; cd2 recomputed in body)
            int f = fg * 256 + tid;
            float4 bft = bp4[f];
            float cdx = bi.x - bft.x, cdy = bi.y - bft.y, cdz = bi.z - bft.z;
            float cd2 = cdx * cdx + cdy * cdy + cdz * cdz;
            bool pass = (f != i) && (cd2 <= GATE2);
            unsigned long long mask = __ballot(pass);
            if (lane == 0) scnt[wid] = __popcll(mask);
            __syncthreads();
            int base = 0;
#pragma unroll
            for (int w = 0; w < 4; ++w) base += (w < wid) ? scnt[w] : 0;
            int nCand = scnt[0] + scnt[1] + scnt[2] + scnt[3];
            int pfx = __popcll(mask & ((1ULL << lane) - 1ULL));
            if (pass) slist[base + pfx] = tid;
            __syncthreads();

            if (tid < nCand) {
                int src = slist[tid];
                float4 bf = bp4[fg * 256 + src];
                float rcx = bi.x - bf.x, rcy = bi.y - bf.y, rcz = bi.z - bf.z;
                float gate = __expf(-10.0f * (rcx * rcx + rcy * rcy + rcz * rcz));
                float tf9[9];
#pragma unroll
                for (int v = 0; v < 9; ++v) tf9[v] = sTri[src * 9 + v];
                float s0 = nix * tf9[0] + niy * tf9[1] + niz * tf9[2] - di;
                float s1 = nix * tf9[3] + niy * tf9[4] + niz * tf9[5] - di;
                float s2 = nix * tf9[6] + niy * tf9[7] + niz * tf9[8] - di;
                float smax = fmaxf(fmaxf(s0, s1), s2);
                float smin = fminf(fminf(s0, s1), s2);
                float pen_col = fmaxf(-(smax * smin), 0.0f);
                float dp = fabsf(nix * bf.x + niy * bf.y + niz * bf.z - di);
                float pen_ov = fmaxf(HPARAM - dp, 0.0f);
                // f-edge invariants
                float q2x[3], q2y[3], q2z[3], e2xa[3], e2ya[3], e2za[3], eva[3], reva[3];
#pragma unroll
                for (int e2 = 0; e2 < 3; ++e2) {
                    int e2n = (e2 == 2) ? 0 : e2 + 1;
                    q2x[e2] = tf9[e2 * 3]; q2y[e2] = tf9[e2 * 3 + 1]; q2z[e2] = tf9[e2 * 3 + 2];
                    e2xa[e2] = tf9[e2n * 3] - q2x[e2];
                    e2ya[e2] = tf9[e2n * 3 + 1] - q2y[e2];
                    e2za[e2] = tf9[e2n * 3 + 2] - q2z[e2];
                    eva[e2] = e2xa[e2] * e2xa[e2] + e2ya[e2] * e2ya[e2] + e2za[e2] * e2za[e2];
                    reva[e2] = __builtin_amdgcn_rcpf(eva[e2] + EPSF);
                }
                float d2v[9];
                float dminv = 3.4e38f;
#pragma unroll
                for (int e1 = 0; e1 < 3; ++e1) {
#pragma unroll
                    for (int e2 = 0; e2 < 3; ++e2) {
                        float rx = p1xa[e1] - q2x[e2], ry = p1ya[e1] - q2y[e2], rz = p1za[e1] - q2z[e2];
                        float f_ = e2xa[e2] * rx + e2ya[e2] * ry + e2za[e2] * rz;
                        float c_ = d1xa[e1] * rx + d1ya[e1] * ry + d1za[e1] * rz;
                        float b_ = d1xa[e1] * e2xa[e2] + d1ya[e1] * e2ya[e2] + d1za[e1] * e2za[e2];
                        float denom = ava[e1] * eva[e2] - b_ * b_;
                        float rden = __builtin_amdgcn_rcpf(denom + EPSF);
                        float ss = clamp01(fmaf(-c_, eva[e2], b_ * f_) * rden);
                        float tt = clamp01(fmaf(b_, ss, f_) * reva[e2]);
                        ss = clamp01(fmaf(b_, tt, -c_) * rava[e1]);
                        float vx = fmaf(ss, d1xa[e1], p1xa[e1]) - fmaf(tt, e2xa[e2], q2x[e2]);
                        float vy = fmaf(ss, d1ya[e1], p1ya[e1]) - fmaf(tt, e2ya[e2], q2y[e2]);
                        float vz = fmaf(ss, d1za[e1], p1za[e1]) - fmaf(tt, e2za[e2], q2z[e2]);
                        float dd = vx * vx + vy * vy + vz * vz;
                        d2v[e1 * 3 + e2] = dd;
                        dminv = fminf(dminv, dd);
                    }
                }
                float pen_edge = 0.0f;
                // relu(H - sqrt(d2+eps)) > 0  <=>  d2 + eps < H^2  (exact)
                if (dminv + EPSF < HPARAM * HPARAM) {
#pragma unroll
                    for (int qq = 0; qq < 9; ++qq)
                        pen_edge += fmaxf(HPARAM - __builtin_amdgcn_sqrtf(d2v[qq] + EPSF), 0.0f);
                }
                contrib += pi * gate * (pen_col + pen_ov + pen_edge);
            }
            __syncthreads();   // protect slist/scnt before next i
        }
        float s = blockSum(contrib, red4);
        if (tid == 0) pairp[rb] = s;
    } else if (b < o2) {
        // ---- surfA: FB faces (regs) x NC target chunks; 4-op inner, psq deferred ----
        int rb = b - o1;
        int fg = rb & 63, chunk = rb >> 6;
        int i0 = fg * FB;
        float m2x[FB], m2y[FB], m2z[FB], m[FB];
#pragma unroll
        for (int k = 0; k < FB; ++k) {
            float4 bb = bp4[i0 + k];
            m2x[k] = -2.0f * bb.x; m2y[k] = -2.0f * bb.y; m2z[k] = -2.0f * bb.z;
            m[k] = 3.4e38f;
        }
        int TC = Ft / NC;
        int jend = chunk * TC + TC;
        for (int j = chunk * TC + tid; j < jend; j += 256) {
            float4 t = bt4[j];
#pragma unroll
            for (int k = 0; k < FB; ++k) {
                float acc = fmaf(m2x[k], t.x, fmaf(m2y[k], t.y, fmaf(m2z[k], t.z, t.w)));
                m[k] = fminf(m[k], acc);
            }
        }
        __shared__ float redA[4][FB];
#pragma unroll
        for (int k = 0; k < FB; ++k) m[k] = waveReduceMin(m[k]);
        int lane = tid & 63, wid = tid >> 6;
        if (lane == 0) {
#pragma unroll
            for (int k = 0; k < FB; ++k) redA[wid][k] = m[k];
        }
        __syncthreads();
        if (tid < FB) {
            float r = fminf(fminf(redA[0][tid], redA[1][tid]),
                            fminf(redA[2][tid], redA[3][tid]));
            surfAp[(i0 + tid) * NC + chunk] = r + bp4[i0 + tid].w;   // defer psq
        }
    } else if (b < o3) {
        // ---- surfB: TT=8 targets/thread, transformed pred chunk in LDS ----
        int rb = b - o2;
        int nJG = Ft / (256 * TT);        // 32
        int jg = rb % nJG, c = rb / nJG;
        int CH = F / ncS;
        for (int t = tid; t < CH; t += 256) {
            float4 p = bp4[c * CH + t];
            sh4[t] = make_float4(-2.0f * p.x, -2.0f * p.y, -2.0f * p.z, p.w);
        }
        __syncthreads();
        int q = Ft / TT;                  // 8192
        int j0 = jg * 256 + tid;
        float4 tv8[TT];
        float mm[TT];
#pragma unroll
        for (int k = 0; k < TT; ++k) { tv8[k] = bt4[j0 + k * q]; mm[k] = 3.4e38f; }
#pragma unroll 2
        for (int i = 0; i < CH; ++i) {
            float4 p = sh4[i];
#pragma unroll
            for (int k = 0; k < TT; ++k)
                mm[k] = fminf(mm[k], fmaf(p.x, tv8[k].x, fmaf(p.y, tv8[k].y, fmaf(p.z, tv8[k].z, p.w))));
        }
#pragma unroll
        for (int k = 0; k < TT; ++k)
            surfBp[c * Ft + j0 + k * q] = mm[k] + tv8[k].w;   // defer |t|^2
    } else if (b < o4) {
        // ---- chamA: VB verts (regs) x NCM target chunks; 4-op inner, psq deferred ----
        int rb = b - o3;
        int vg = rb & 63, chunk = rb >> 6;
        int v0 = vg * VB;
        float m2x[VB], m2y[VB], m2z[VB], m[VB];
#pragma unroll
        for (int k = 0; k < VB; ++k) {
            float4 p = pv4[v0 + k];
            m2x[k] = -2.0f * p.x; m2y[k] = -2.0f * p.y; m2z[k] = -2.0f * p.z;
            m[k] = 3.4e38f;
        }
        int TC = M / NCM;
        int jend = chunk * TC + TC;
        for (int j = chunk * TC + tid; j < jend; j += 256) {
            float4 t = tv4[j];
#pragma unroll
            for (int k = 0; k < VB; ++k) {
                float acc = fmaf(m2x[k], t.x, fmaf(m2y[k], t.y, fmaf(m2z[k], t.z, t.w)));
                m[k] = fminf(m[k], acc);
            }
        }
        __shared__ float redC[4][VB];
#pragma unroll
        for (int k = 0; k < VB; ++k) m[k] = waveReduceMin(m[k]);
        int lane = tid & 63, wid = tid >> 6;
        if (lane == 0) {
#pragma unroll
            for (int k = 0; k < VB; ++k) redC[wid][k] = m[k];
        }
        __syncthreads();
        if (tid < VB) {
            float r = fminf(fminf(redC[0][tid], redC[1][tid]),
                            fminf(redC[2][tid], redC[3][tid]));
            chamAp[(v0 + tid) * NCM + chunk] = r + pv4[v0 + tid].w;
        }
    } else {
        // ---- chamB: TT=8 targets/thread, transformed vert chunk in LDS ----
        int rb = b - o4;
        int nJG = M / (256 * TT);         // 16
        int jg = rb % nJG, c = rb / nJG;
        int CH = N / ncC;
        for (int t = tid; t < CH; t += 256) {
            float4 p = pv4[c * CH + t];
            sh4[t] = make_float4(-2.0f * p.x, -2.0f * p.y, -2.0f * p.z, p.w);
        }
        __syncthreads();
        int q = M / TT;                   // 4096
        int j0 = jg * 256 + tid;
        float4 tv8[TT];
        float mm[TT];
#pragma unroll
        for (int k = 0; k < TT; ++k) { tv8[k] = tv4[j0 + k * q]; mm[k] = 3.4e38f; }
#pragma unroll 2
        for (int i = 0; i < CH; ++i) {
            float4 p = sh4[i];
#pragma unroll
            for (int k = 0; k < TT; ++k)
                mm[k] = fminf(mm[k], fmaf(p.x, tv8[k].x, fmaf(p.y, tv8[k].y, fmaf(p.z, tv8[k].z, p.w))));
        }
#pragma unroll
        for (int k = 0; k < TT; ++k)
            chamBp[c * M + j0 + k * q] = mm[k] + tv8[k].w;
    }
}

// ---------------- generic reduce: every block emits one weighted partial ----------------
__global__ __launch_bounds__(256) void k_reduce(
    const float* __restrict__ surfBp, int Ft, int ncS, float invFt,
    const float* __restrict__ chamBp, int M, int ncC, float invM,
    const float* __restrict__ chamAp, int N, float invN,
    const float* __restrict__ surfAp, const float* __restrict__ probs, int F, float invF,
    const float* __restrict__ pairp, int nPB, float pairScale,
    float* __restrict__ smallp)
{
    __shared__ float red4[4];
    int b = blockIdx.x, tid = threadIdx.x;
    int nbS = Ft >> 8, nbC = M >> 8, nbA = N >> 8, nbSA = F >> 8;
    float s;
    if (b < nbS) {
        int j = b * 256 + tid;
        float r = 3.4e38f;
        for (int c = 0; c < ncS; ++c) r = fminf(r, surfBp[c * Ft + j]);
        s = r * invFt;
    } else if (b < nbS + nbC) {
        int j = (b - nbS) * 256 + tid;
        float r = 3.4e38f;
        for (int c = 0; c < ncC; ++c) r = fminf(r, chamBp[c * M + j]);
        s = r * invM;
    } else if (b < nbS + nbC + nbA) {
        int v = (b - nbS - nbC) * 256 + tid;
        float r = 3.4e38f;
#pragma unroll
        for (int c = 0; c < NCM; ++c) r = fminf(r, chamAp[v * NCM + c]);
        s = r * invN;
    } else if (b < nbS + nbC + nbA + nbSA) {
        int i = (b - nbS - nbC - nbA) * 256 + tid;
        float r = 3.4e38f;
#pragma unroll
        for (int c = 0; c < NC; ++c) r = fminf(r, surfAp[i * NC + c]);
        s = probs[i] * r * invF;
    } else {
        int t = (b - nbS - nbC - nbA - nbSA) * 256 + tid;
        s = (t < nPB) ? pairp[t] * pairScale : 0.0f;
    }
    float r = blockSum(s, red4);
    if (tid == 0) smallp[b] = r;
}

// ---------------- tiny final sum ----------------
__global__ __launch_bounds__(256) void k_fin(
    const float* __restrict__ smallp, int n, float* __restrict__ out)
{
    __shared__ float red4[4];
    float s = 0.0f;
    for (int t = threadIdx.x; t < n; t += 256) s += smallp[t];
    float r = blockSum(s, red4);
    if (threadIdx.x == 0) out[0] = r;
}

extern "C" void kernel_launch(void* const* d_in, const int* in_sizes, int n_in,
                              void* d_out, int out_size, void* d_ws, size_t ws_size,
                              hipStream_t stream) {
    const float* pv    = (const float*)d_in[0];
    const float* probs = (const float*)d_in[1];
    const float* tv    = (const float*)d_in[2];
    const int*   pf    = (const int*)d_in[3];
    const int*   tf    = (const int*)d_in[4];
    float* out = (float*)d_out;

    int N  = in_sizes[0] / 3;   // 512
    int F  = in_sizes[1];       // 1024
    int M  = in_sizes[2] / 3;   // 32768
    int Ft = in_sizes[4] / 3;   // 65536

    int bpF = F >> 8;                 // 4
    int nPB = (F / TI) * bpF;         // 1024 pair blocks

    size_t baseFloats = (size_t)F * 13 + (size_t)F * 4 + (size_t)Ft * 4
                      + (size_t)M * 4 + (size_t)N * 4
                      + (size_t)N * NCM + (size_t)F * NC + (size_t)nPB + 512;
    int ncS = 8, ncC = 8;
    if (ws_size < (baseFloats + (size_t)8 * Ft + (size_t)8 * M) * 4) {
        ncS = 2; ncC = 2;
        if (ws_size < (baseFloats + (size_t)2 * Ft + (size_t)2 * M) * 4) { ncS = 1; ncC = 1; }
    }

    float* ws = (float*)d_ws;
    float* w_tri    = ws;                       // F*9
    float* w_nhat   = w_tri + F * 9;            // F*3
    float* w_d0     = w_nhat + F * 3;           // F
    float4* w_bp4   = (float4*)(w_d0 + F);      // F (16B aligned)
    float4* w_bt4   = w_bp4 + F;                // Ft
    float4* w_tv4   = w_bt4 + Ft;               // M
    float4* w_pv4   = w_tv4 + M;                // N
    float* w_chamAp = (float*)(w_pv4 + N);      // N*NCM
    float* w_surfAp = w_chamAp + N * NCM;       // F*NC
    float* w_pair   = w_surfAp + F * NC;        // nPB
    float* w_small  = w_pair + nPB;             // <=512
    float* w_surfBp = w_small + 512;            // ncS*Ft
    float* w_chamBp = w_surfBp + (size_t)ncS * Ft; // ncC*M

    // mega-grid role offsets: pair FIRST, then surfA, surfB, chamA, chamB
    int o1 = nPB;                            // 1024 pair
    int o2 = o1 + (F / FB) * NC;             // +1024 surfA
    int o3 = o2 + (Ft / (256 * TT)) * ncS;   // +256 surfB
    int o4 = o3 + (N / VB) * NCM;            // +1024 chamA
    int gTot = o4 + (M / (256 * TT)) * ncC;  // +128 chamB

    int nSmall = (Ft >> 8) + (M >> 8) + (N >> 8) + (F >> 8) + ((nPB + 255) >> 8); // 394
    int gPre = (F + 255) / 256 + (Ft + 255) / 256 + (M + 255) / 256 + (N + 255) / 256;

    k_pre<<<gPre, 256, 0, stream>>>(
        pv, pf, tv, tf, w_tri, w_bp4, w_nhat, w_d0, w_bt4, w_tv4, w_pv4,
        N, F, M, Ft);
    k_mega<<<gTot, 256, 0, stream>>>(
        w_pv4, w_tv4, w_tri, w_bp4, w_nhat, w_d0, probs, w_bt4,
        w_chamAp, w_chamBp, w_surfAp, w_surfBp, w_pair,
        N, F, M, Ft, ncS, ncC, o1, o2, o3, o4);
    k_reduce<<<nSmall, 256, 0, stream>>>(
        w_surfBp, Ft, ncS, 1.0f / (float)Ft,
        w_chamBp, M, ncC, 1.0f / (float)M,
        w_chamAp, N, 1.0f / (float)N,
        w_surfAp, probs, F, 1.0f / (float)F,
        w_pair, nPB, 10.0f / (float)F,
        w_small);
    k_fin<<<1, 256, 0, stream>>>(w_small, nSmall, out);
}